// Round 8
// baseline (945.681 us; speedup 1.0000x reference)
//
#include <hip/hip_runtime.h>
#include <hip/hip_fp16.h>

#define NN 100000
#define NE 1600000
#define BK 512          // nodes per bucket (CSR build)
#define BKSH 9          // log2(BK)
#define NBKT 196        // ceil(NN/BK)

// ---------------- Bucketed CSR build (unchanged from R7) ----------------

__global__ __launch_bounds__(256) void zero_small_kernel(int* __restrict__ p, int n) {
    int i = threadIdx.x + blockIdx.x * 256;
    if (i < n) p[i] = 0;
}

__global__ __launch_bounds__(256) void bhist_kernel(const int* __restrict__ dst,
                                                    int* __restrict__ bcnt, int e) {
    __shared__ int h[4 * NBKT];
    int tid = threadIdx.x;
    int wv = tid >> 6;
    for (int i = tid; i < 4 * NBKT; i += 256) h[i] = 0;
    __syncthreads();
    for (int i = blockIdx.x * 256 + tid; i < e; i += gridDim.x * 256)
        atomicAdd(&h[wv * NBKT + (__builtin_nontemporal_load(&dst[i]) >> BKSH)], 1);
    __syncthreads();
    for (int i = tid; i < NBKT; i += 256) {
        int s = h[i] + h[NBKT + i] + h[2 * NBKT + i] + h[3 * NBKT + i];
        if (s) atomicAdd(&bcnt[i], s);
    }
}

__global__ __launch_bounds__(256) void bscan_kernel(const int* __restrict__ bcnt,
                                                    int* __restrict__ bbase,
                                                    int* __restrict__ bcur) {
    __shared__ int sc[256];
    int tid = threadIdx.x;
    int v = (tid < NBKT) ? bcnt[tid] : 0;
    sc[tid] = v;
    __syncthreads();
    for (int off = 1; off < 256; off <<= 1) {
        int t2 = (tid >= off) ? sc[tid - off] : 0;
        __syncthreads();
        sc[tid] += t2;
        __syncthreads();
    }
    if (tid < NBKT) {
        int ex = sc[tid] - v;
        bbase[tid] = ex;
        bcur[tid] = ex;
    }
    if (tid == 255) bbase[NBKT] = sc[255];
}

__global__ __launch_bounds__(256) void bscatter_kernel(const int* __restrict__ src,
                                                       const int* __restrict__ dst,
                                                       int* __restrict__ bcur,
                                                       int2* __restrict__ bedges, int e) {
    __shared__ int h[256];
    __shared__ int sc[256];
    __shared__ int gb[NBKT];
    __shared__ int2 stage[2048];
    int tid = threadIdx.x;
    for (int tile = blockIdx.x * 2048; tile < e; tile += gridDim.x * 2048) {
        int cnt_tile = min(2048, e - tile);
        h[tid] = 0;
        __syncthreads();
        int2 pr[8]; int rk[8]; int bk[8];
#pragma unroll
        for (int j = 0; j < 8; j++) {
            int li = tid + j * 256;
            if (li < cnt_tile) {
                pr[j].x = src[tile + li];
                pr[j].y = dst[tile + li];
                bk[j] = pr[j].y >> BKSH;
                rk[j] = atomicAdd(&h[bk[j]], 1);
            } else bk[j] = -1;
        }
        __syncthreads();
        int v = h[tid];
        sc[tid] = v;
        __syncthreads();
        for (int off = 1; off < 256; off <<= 1) {
            int t2 = (tid >= off) ? sc[tid - off] : 0;
            __syncthreads();
            sc[tid] += t2;
            __syncthreads();
        }
        int excl = sc[tid] - v;
        if (tid < NBKT && v > 0) gb[tid] = atomicAdd(&bcur[tid], v);
        __syncthreads();
        sc[tid] = excl;
        __syncthreads();
#pragma unroll
        for (int j = 0; j < 8; j++)
            if (bk[j] >= 0) stage[sc[bk[j]] + rk[j]] = pr[j];
        __syncthreads();
#pragma unroll
        for (int j = 0; j < 8; j++) {
            int li = tid + j * 256;
            if (li < cnt_tile) {
                int2 p2 = stage[li];
                int b = p2.y >> BKSH;
                bedges[gb[b] + (li - sc[b])] = p2;
            }
        }
        __syncthreads();
    }
}

__global__ __launch_bounds__(256) void bfill_kernel(const int2* __restrict__ bedges,
                                                    const int* __restrict__ bbase,
                                                    int* __restrict__ start,
                                                    int* __restrict__ cnt,
                                                    float* __restrict__ dinv,
                                                    int* __restrict__ csr) {
    __shared__ int lcnt[BK];
    __shared__ int lsum[256];
    __shared__ int lstart[BK];
    __shared__ int lcur[BK];
    int q = blockIdx.x, tid = threadIdx.x;
    int ebase = bbase[q], ec = bbase[q + 1] - ebase;
    int nbase = q * BK;
    lcnt[tid] = 0; lcnt[tid + 256] = 0;
    __syncthreads();
    for (int i = tid; i < ec; i += 256)
        atomicAdd(&lcnt[bedges[ebase + i].y - nbase], 1);
    __syncthreads();
    int a = lcnt[2 * tid], b = lcnt[2 * tid + 1];
    int s = a + b;
    lsum[tid] = s;
    __syncthreads();
    for (int off = 1; off < 256; off <<= 1) {
        int t2 = (tid >= off) ? lsum[tid - off] : 0;
        __syncthreads();
        lsum[tid] += t2;
        __syncthreads();
    }
    int ex = lsum[tid] - s;
    lstart[2 * tid] = ex;       lstart[2 * tid + 1] = ex + a;
    lcur[2 * tid] = ex;         lcur[2 * tid + 1] = ex + a;
    __syncthreads();
    for (int l = tid; l < BK; l += 256) {
        int v = nbase + l;
        if (v < NN) {
            start[v] = ebase + lstart[l];
            cnt[v]   = lcnt[l];
            dinv[v]  = rsqrtf((float)lcnt[l] + 1.0f);
        }
    }
    for (int i = tid; i < ec; i += 256) {
        int2 p2 = bedges[ebase + i];
        int r = atomicAdd(&lcur[p2.y - nbase], 1);
        csr[ebase + r] = p2.x;
    }
}

// ---------------- prep: g0 = fp16(dinv .* x) ----------------
__global__ __launch_bounds__(256) void prep_kernel(const float* __restrict__ x,
                                                   const float* __restrict__ dinv,
                                                   __half* __restrict__ g) {
    size_t i4 = (size_t)blockIdx.x * 256 + threadIdx.x;   // float4 index
    if (i4 >= (size_t)NN * 16) return;
    int row = (int)(i4 >> 4);
    float dv = dinv[row];
    float4 v = *(const float4*)&x[i4 * 4];
    __half2 h01 = __floats2half2_rn(v.x * dv, v.y * dv);
    __half2 h23 = __floats2half2_rn(v.z * dv, v.w * dv);
    __half2* gp = (__half2*)&g[i4 * 4];
    gp[0] = h01;
    gp[1] = h23;
}

// ---------------- Fused layer (1-3): gather + 64x64 transform ----------------
// 256 threads = 4 waves, each wave owns 4 nodes end-to-end (no cross-wave
// barrier after W staging). W packed as float4 quads wq[q][c] = W[4q..4q+3][c]
// so the matvec is 1 per-lane b128 W read per l-quad amortized over 4 nodes.
__global__ __launch_bounds__(256) void fused_layer_kernel(const __half* __restrict__ g,
                                                          const int* __restrict__ csr,
                                                          const int* __restrict__ start,
                                                          const int* __restrict__ cnt,
                                                          const float* __restrict__ dinv,
                                                          const float* __restrict__ Wg,
                                                          const float* __restrict__ bias,
                                                          __half* __restrict__ gout, int n) {
    __shared__ float4 wq[16][64];    // 16KB: W[l][c] packed by l-quad
    __shared__ float zs[4][4][64];   // 4KB: per-wave z rows (wave-private)
    __shared__ float bs[64];
    int tid = threadIdx.x;
    // stage W: idx = q*64+c ; wq[q][c] = {W[4q][c],W[4q+1][c],W[4q+2][c],W[4q+3][c]}
    for (int idx = tid; idx < 1024; idx += 256) {
        int q = idx >> 6, c = idx & 63;
        wq[q][c] = make_float4(Wg[(4 * q + 0) * 64 + c], Wg[(4 * q + 1) * 64 + c],
                               Wg[(4 * q + 2) * 64 + c], Wg[(4 * q + 3) * 64 + c]);
    }
    if (tid < 64) bs[tid] = bias[tid];
    __syncthreads();   // only barrier: W/bias visible to all waves

    int wv = tid >> 6, lane = tid & 63;
    int nb = blockIdx.x * 16 + wv * 4;
    float dv[4];
    float acc[4];
#pragma unroll
    for (int i = 0; i < 4; i++) {
        int node = nb + i;
        acc[i] = 0.f; dv[i] = 0.f;
        if (node < n) {
            int st = __builtin_amdgcn_readfirstlane(start[node]);
            int cn = __builtin_amdgcn_readfirstlane(cnt[node]);
            dv[i] = dinv[node];
            float a0 = __half2float(g[(size_t)node * 64 + lane]);  // self loop
            float acc_l = a0;
            int e = 0;
            for (; e + 7 < cn; e += 8) {
                int u[8]; float a[8];
#pragma unroll
                for (int j = 0; j < 8; j++) u[j] = __builtin_nontemporal_load(&csr[st + e + j]);
#pragma unroll
                for (int j = 0; j < 8; j++) a[j] = __half2float(g[(size_t)u[j] * 64 + lane]);
                acc_l += ((a[0] + a[1]) + (a[2] + a[3])) + ((a[4] + a[5]) + (a[6] + a[7]));
            }
            for (; e + 3 < cn; e += 4) {
                int u0 = __builtin_nontemporal_load(&csr[st + e + 0]);
                int u1 = __builtin_nontemporal_load(&csr[st + e + 1]);
                int u2 = __builtin_nontemporal_load(&csr[st + e + 2]);
                int u3 = __builtin_nontemporal_load(&csr[st + e + 3]);
                float a0_ = __half2float(g[(size_t)u0 * 64 + lane]);
                float a1_ = __half2float(g[(size_t)u1 * 64 + lane]);
                float a2_ = __half2float(g[(size_t)u2 * 64 + lane]);
                float a3_ = __half2float(g[(size_t)u3 * 64 + lane]);
                acc_l += (a0_ + a1_) + (a2_ + a3_);
            }
            for (; e < cn; e++) {
                int u = __builtin_nontemporal_load(&csr[st + e]);
                acc_l += __half2float(g[(size_t)u * 64 + lane]);
            }
            acc[i] = acc_l;
        }
        zs[wv][i][lane] = acc[i];   // wave-private row: no barrier needed
    }

    // matvec: t[i][lane] = sum_l zs[wv][i][l] * W[l][lane]
    float t[4] = {0.f, 0.f, 0.f, 0.f};
#pragma unroll
    for (int q = 0; q < 16; q++) {
        float4 wv4 = wq[q][lane];                       // per-lane b128
#pragma unroll
        for (int i = 0; i < 4; i++) {
            float4 zq = *(const float4*)&zs[wv][i][q * 4];  // uniform b128
            t[i] += zq.x * wv4.x + zq.y * wv4.y + zq.z * wv4.z + zq.w * wv4.w;
        }
    }
#pragma unroll
    for (int i = 0; i < 4; i++) {
        int node = nb + i;
        if (node < n) {
            float o = dv[i] * t[i] + bs[lane];
            o = fmaxf(o, 0.f);
            gout[(size_t)node * 64 + lane] = __float2half_rn(dv[i] * o);
        }
    }
}

// ---------------- Layer-4 transform: s4 = g3 @ W4  (dinv cancels exactly) ----------------
__global__ __launch_bounds__(128) void gemm16_kernel(const __half* __restrict__ xin,
                                                     const float* __restrict__ W,
                                                     __half* __restrict__ s, int n) {
    constexpr int DOUT = 16;
    constexpr int ROWS = 128;
    __shared__ float xs[ROWS][65];
    __shared__ float ws[64][DOUT];
    int tid = threadIdx.x;
    int row0 = blockIdx.x * ROWS;
    for (int i = tid; i < 64 * DOUT; i += 128) ws[i / DOUT][i % DOUT] = W[i];
    for (int i = tid; i < ROWS * 16; i += 128) {
        int r = i >> 4, c = (i & 15) * 4;
        float4 v = make_float4(0.f, 0.f, 0.f, 0.f);
        if (row0 + r < n) {
            const __half* hp = xin + (size_t)(row0 + r) * 64 + c;
            float2 f01 = __half22float2(*(const __half2*)hp);
            float2 f23 = __half22float2(*(const __half2*)(hp + 2));
            v = make_float4(f01.x, f01.y, f23.x, f23.y);
        }
        xs[r][c] = v.x; xs[r][c + 1] = v.y; xs[r][c + 2] = v.z; xs[r][c + 3] = v.w;
    }
    __syncthreads();
    int rbase = tid;           // 1 row per thread
    float acc[16];
#pragma unroll
    for (int j = 0; j < 16; j++) acc[j] = 0.f;
    for (int k = 0; k < 64; k++) {
        float xv = xs[rbase][k];
#pragma unroll
        for (int j = 0; j < 4; j++) {
            float4 wv = *(const float4*)&ws[k][j * 4];
            acc[j * 4 + 0] += xv * wv.x;
            acc[j * 4 + 1] += xv * wv.y;
            acc[j * 4 + 2] += xv * wv.z;
            acc[j * 4 + 3] += xv * wv.w;
        }
    }
    int r = row0 + rbase;
    if (r < n) {
        union { ushort u[16]; uint4 q[2]; } pk;
#pragma unroll
        for (int j = 0; j < 16; j++)
            pk.u[j] = __half_as_ushort(__float2half_rn(acc[j]));
        uint4* sp = (uint4*)&s[(size_t)r * DOUT];
        sp[0] = pk.q[0];
        sp[1] = pk.q[1];
    }
}

// ---------------- Layer-4 aggregate: out = dinv*(sum s4) + b4, fp32 ----------------
__global__ __launch_bounds__(256) void agg16_kernel(const __half* __restrict__ s,
                                                    const int* __restrict__ csr,
                                                    const int* __restrict__ start,
                                                    const int* __restrict__ cnt,
                                                    const float* __restrict__ dinv,
                                                    const float* __restrict__ bias,
                                                    float* __restrict__ out, int n) {
    constexpr int D = 16;
    int tid = threadIdx.x;
    int lane = tid & 63;
    int wave = tid >> 6;
    int col = lane % D;
    int grp = lane / D;
    int node = (blockIdx.x * 4 + wave) * 4 + grp;
    if (node >= n) return;
    int st = start[node];
    int cn = cnt[node];
    float acc = __half2float(s[(size_t)node * D + col]);  // self loop
    int e = 0;
    for (; e + 7 < cn; e += 8) {
        int u[8]; float a[8];
#pragma unroll
        for (int j = 0; j < 8; j++) u[j] = __builtin_nontemporal_load(&csr[st + e + j]);
#pragma unroll
        for (int j = 0; j < 8; j++) a[j] = __half2float(s[(size_t)u[j] * D + col]);
        acc += ((a[0] + a[1]) + (a[2] + a[3])) + ((a[4] + a[5]) + (a[6] + a[7]));
    }
    for (; e + 3 < cn; e += 4) {
        int u0 = __builtin_nontemporal_load(&csr[st + e + 0]);
        int u1 = __builtin_nontemporal_load(&csr[st + e + 1]);
        int u2 = __builtin_nontemporal_load(&csr[st + e + 2]);
        int u3 = __builtin_nontemporal_load(&csr[st + e + 3]);
        float a0 = __half2float(s[(size_t)u0 * D + col]);
        float a1 = __half2float(s[(size_t)u1 * D + col]);
        float a2 = __half2float(s[(size_t)u2 * D + col]);
        float a3 = __half2float(s[(size_t)u3 * D + col]);
        acc += (a0 + a1) + (a2 + a3);
    }
    for (; e < cn; e++) {
        int u = __builtin_nontemporal_load(&csr[st + e]);
        acc += __half2float(s[(size_t)u * D + col]);
    }
    float o = dinv[node] * acc + bias[col];
    __builtin_nontemporal_store(o, out + (size_t)node * D + col);
}

// ---------------- launch ----------------

extern "C" void kernel_launch(void* const* d_in, const int* in_sizes, int n_in,
                              void* d_out, int out_size, void* d_ws, size_t ws_size,
                              hipStream_t stream) {
    const float* x  = (const float*)d_in[0];
    const int* ei   = (const int*)d_in[1];
    const float* W1 = (const float*)d_in[2];
    const float* b1 = (const float*)d_in[3];
    const float* W2 = (const float*)d_in[4];
    const float* b2 = (const float*)d_in[5];
    const float* W3 = (const float*)d_in[6];
    const float* b3 = (const float*)d_in[7];
    const float* W4 = (const float*)d_in[8];
    const float* b4 = (const float*)d_in[9];
    const int* src = ei;
    const int* dst = ei + NE;

    char* w = (char*)d_ws;
    float* dinv  = (float*)w;         w += (size_t)NN * 4;
    int* cnt     = (int*)w;           w += (size_t)NN * 4;
    int* start   = (int*)w;           w += (size_t)NN * 4;
    int* bcnt    = (int*)w;           w += (size_t)(NBKT + 4) * 4;
    int* bbase   = (int*)w;           w += (size_t)(NBKT + 4) * 4;
    int* bcur    = (int*)w;           w += (size_t)(NBKT + 4) * 4;
    int* csr     = (int*)w;           w += (size_t)NE * 4;
    __half* gA   = (__half*)w;        w += (size_t)NN * 64 * 2;
    __half* gB   = (__half*)w;        w += (size_t)NN * 64 * 2;
    __half* s4   = (__half*)w;        w += (size_t)NN * 16 * 2;
    int2* bedges = (int2*)w;          w += (size_t)NE * 8;

    zero_small_kernel<<<1, 256, 0, stream>>>(bcnt, NBKT);
    bhist_kernel<<<512, 256, 0, stream>>>(dst, bcnt, NE);
    bscan_kernel<<<1, 256, 0, stream>>>(bcnt, bbase, bcur);
    bscatter_kernel<<<512, 256, 0, stream>>>(src, dst, bcur, bedges, NE);
    bfill_kernel<<<NBKT, 256, 0, stream>>>(bedges, bbase, start, cnt, dinv, csr);

    prep_kernel<<<(NN * 16 + 255) / 256, 256, 0, stream>>>(x, dinv, gA);

    const int FB = (NN + 15) / 16;    // 6250 blocks, 16 nodes each (4/wave)
    fused_layer_kernel<<<FB, 256, 0, stream>>>(gA, csr, start, cnt, dinv, W1, b1, gB, NN);
    fused_layer_kernel<<<FB, 256, 0, stream>>>(gB, csr, start, cnt, dinv, W2, b2, gA, NN);
    fused_layer_kernel<<<FB, 256, 0, stream>>>(gA, csr, start, cnt, dinv, W3, b3, gB, NN);

    const int GB = (NN + 127) / 128;
    const int AB16 = (NN + 15) / 16;
    gemm16_kernel<<<GB, 128, 0, stream>>>(gB, W4, s4, NN);
    agg16_kernel<<<AB16, 256, 0, stream>>>(s4, csr, start, cnt, dinv, b4, (float*)d_out, NN);
}

// Round 9
// 381.832 us; speedup vs baseline: 2.4767x; 2.4767x over previous
//
#include <hip/hip_runtime.h>
#include <hip/hip_fp16.h>

#define NN 100000
#define NE 1600000
#define BK 512          // nodes per bucket (CSR build)
#define BKSH 9          // log2(BK)
#define NBKT 196        // ceil(NN/BK)

// ---------------- Bucketed CSR build ----------------

__global__ __launch_bounds__(256) void zero_small_kernel(int* __restrict__ p, int n) {
    int i = threadIdx.x + blockIdx.x * 256;
    if (i < n) p[i] = 0;
}

__global__ __launch_bounds__(256) void bhist_kernel(const int* __restrict__ dst,
                                                    int* __restrict__ bcnt, int e) {
    __shared__ int h[4 * NBKT];
    int tid = threadIdx.x;
    int wv = tid >> 6;
    for (int i = tid; i < 4 * NBKT; i += 256) h[i] = 0;
    __syncthreads();
    for (int i = blockIdx.x * 256 + tid; i < e; i += gridDim.x * 256)
        atomicAdd(&h[wv * NBKT + (__builtin_nontemporal_load(&dst[i]) >> BKSH)], 1);
    __syncthreads();
    for (int i = tid; i < NBKT; i += 256) {
        int s = h[i] + h[NBKT + i] + h[2 * NBKT + i] + h[3 * NBKT + i];
        if (s) atomicAdd(&bcnt[i], s);
    }
}

__global__ __launch_bounds__(256) void bscan_kernel(const int* __restrict__ bcnt,
                                                    int* __restrict__ bbase,
                                                    int* __restrict__ bcur) {
    __shared__ int sc[256];
    int tid = threadIdx.x;
    int v = (tid < NBKT) ? bcnt[tid] : 0;
    sc[tid] = v;
    __syncthreads();
    for (int off = 1; off < 256; off <<= 1) {
        int t2 = (tid >= off) ? sc[tid - off] : 0;
        __syncthreads();
        sc[tid] += t2;
        __syncthreads();
    }
    if (tid < NBKT) {
        int ex = sc[tid] - v;
        bbase[tid] = ex;
        bcur[tid] = ex;
    }
    if (tid == 255) bbase[NBKT] = sc[255];
}

__global__ __launch_bounds__(256) void bscatter_kernel(const int* __restrict__ src,
                                                       const int* __restrict__ dst,
                                                       int* __restrict__ bcur,
                                                       int2* __restrict__ bedges, int e) {
    __shared__ int h[256];
    __shared__ int sc[256];
    __shared__ int gb[NBKT];
    __shared__ int2 stage[2048];
    int tid = threadIdx.x;
    for (int tile = blockIdx.x * 2048; tile < e; tile += gridDim.x * 2048) {
        int cnt_tile = min(2048, e - tile);
        h[tid] = 0;
        __syncthreads();
        int2 pr[8]; int rk[8]; int bk[8];
#pragma unroll
        for (int j = 0; j < 8; j++) {
            int li = tid + j * 256;
            if (li < cnt_tile) {
                pr[j].x = src[tile + li];
                pr[j].y = dst[tile + li];
                bk[j] = pr[j].y >> BKSH;
                rk[j] = atomicAdd(&h[bk[j]], 1);
            } else bk[j] = -1;
        }
        __syncthreads();
        int v = h[tid];
        sc[tid] = v;
        __syncthreads();
        for (int off = 1; off < 256; off <<= 1) {
            int t2 = (tid >= off) ? sc[tid - off] : 0;
            __syncthreads();
            sc[tid] += t2;
            __syncthreads();
        }
        int excl = sc[tid] - v;
        if (tid < NBKT && v > 0) gb[tid] = atomicAdd(&bcur[tid], v);
        __syncthreads();
        sc[tid] = excl;
        __syncthreads();
#pragma unroll
        for (int j = 0; j < 8; j++)
            if (bk[j] >= 0) stage[sc[bk[j]] + rk[j]] = pr[j];
        __syncthreads();
#pragma unroll
        for (int j = 0; j < 8; j++) {
            int li = tid + j * 256;
            if (li < cnt_tile) {
                int2 p2 = stage[li];
                int b = p2.y >> BKSH;
                bedges[gb[b] + (li - sc[b])] = p2;
            }
        }
        __syncthreads();
    }
}

// 512 threads: halves the serial depth of the (196-block, slowest-bucket-bound) fill.
__global__ __launch_bounds__(512) void bfill_kernel(const int2* __restrict__ bedges,
                                                    const int* __restrict__ bbase,
                                                    int* __restrict__ start,
                                                    int* __restrict__ cnt,
                                                    float* __restrict__ dinv,
                                                    int* __restrict__ csr) {
    __shared__ int lcnt[BK];
    __shared__ int lsum[BK];
    __shared__ int lcur[BK];
    int q = blockIdx.x, tid = threadIdx.x;
    int ebase = bbase[q], ec = bbase[q + 1] - ebase;
    int nbase = q * BK;
    lcnt[tid] = 0;
    __syncthreads();
    for (int i = tid; i < ec; i += 512)
        atomicAdd(&lcnt[bedges[ebase + i].y - nbase], 1);
    __syncthreads();
    int s = lcnt[tid];
    lsum[tid] = s;
    __syncthreads();
    for (int off = 1; off < 512; off <<= 1) {
        int t2 = (tid >= off) ? lsum[tid - off] : 0;
        __syncthreads();
        lsum[tid] += t2;
        __syncthreads();
    }
    int ex = lsum[tid] - s;
    lcur[tid] = ex;
    __syncthreads();
    int v = nbase + tid;
    if (v < NN) {
        start[v] = ebase + ex;
        cnt[v]   = s;
        dinv[v]  = rsqrtf((float)s + 1.0f);
    }
    for (int i = tid; i < ec; i += 512) {
        int2 p2 = bedges[ebase + i];
        int r = atomicAdd(&lcur[p2.y - nbase], 1);
        csr[ebase + r] = p2.x;
    }
}

// ---------------- prep: g0 = fp16(dinv .* x) ----------------
__global__ __launch_bounds__(256) void prep_kernel(const float* __restrict__ x,
                                                   const float* __restrict__ dinv,
                                                   __half* __restrict__ g) {
    size_t i4 = (size_t)blockIdx.x * 256 + threadIdx.x;   // float4 index
    if (i4 >= (size_t)NN * 16) return;
    int row = (int)(i4 >> 4);
    float dv = dinv[row];
    float4 v = *(const float4*)&x[i4 * 4];
    __half2 h01 = __floats2half2_rn(v.x * dv, v.y * dv);
    __half2 h23 = __floats2half2_rn(v.z * dv, v.w * dv);
    __half2* gp = (__half2*)&g[i4 * 4];
    gp[0] = h01;
    gp[1] = h23;
}

// ---------------- Fused layer (1-3): gather + 64x64 transform ----------------
// R7 shape (1 node/wave, 8 waves/block, ~20 VGPR) with two fixes:
//  (a) NO post-gather barrier: zs row is wave-private, DS-pipe ordering suffices
//      -> no coupling to the block's slowest node.
//  (b) W packed as float4 quads wq[q][c] = W[4q..4q+3][c]: matvec is
//      16 per-lane ds_read_b128 + 16 uniform b128 per node (was 64 b32 + 16 b128).
__global__ __launch_bounds__(512) void fused_layer_kernel(const __half* __restrict__ g,
                                                          const int* __restrict__ csr,
                                                          const int* __restrict__ start,
                                                          const int* __restrict__ cnt,
                                                          const float* __restrict__ dinv,
                                                          const float* __restrict__ Wg,
                                                          const float* __restrict__ bias,
                                                          __half* __restrict__ gout, int n) {
    __shared__ float4 wq[16][64];   // 16KB
    __shared__ float zs[8][64];     // 2KB, one row per wave
    __shared__ float bs[64];
    int tid = threadIdx.x;
    for (int idx = tid; idx < 1024; idx += 512) {
        int q = idx >> 6, c = idx & 63;
        wq[q][c] = make_float4(Wg[(4 * q + 0) * 64 + c], Wg[(4 * q + 1) * 64 + c],
                               Wg[(4 * q + 2) * 64 + c], Wg[(4 * q + 3) * 64 + c]);
    }
    if (tid < 64) bs[tid] = bias[tid];
    __syncthreads();   // only barrier: W/bias staging

    int wv = tid >> 6, lane = tid & 63;
    int node = blockIdx.x * 8 + wv;
    float acc = 0.f;
    float dv = 0.f;
    if (node < n) {
        int st = __builtin_amdgcn_readfirstlane(start[node]);
        int cn = __builtin_amdgcn_readfirstlane(cnt[node]);
        dv = dinv[node];
        acc = __half2float(g[(size_t)node * 64 + lane]);  // self loop
        int e = 0;
        for (; e + 7 < cn; e += 8) {
            int u[8]; float a[8];
#pragma unroll
            for (int j = 0; j < 8; j++) u[j] = __builtin_nontemporal_load(&csr[st + e + j]);
#pragma unroll
            for (int j = 0; j < 8; j++) a[j] = __half2float(g[(size_t)u[j] * 64 + lane]);
            acc += ((a[0] + a[1]) + (a[2] + a[3])) + ((a[4] + a[5]) + (a[6] + a[7]));
        }
        for (; e + 3 < cn; e += 4) {
            int u0 = __builtin_nontemporal_load(&csr[st + e + 0]);
            int u1 = __builtin_nontemporal_load(&csr[st + e + 1]);
            int u2 = __builtin_nontemporal_load(&csr[st + e + 2]);
            int u3 = __builtin_nontemporal_load(&csr[st + e + 3]);
            float a0 = __half2float(g[(size_t)u0 * 64 + lane]);
            float a1 = __half2float(g[(size_t)u1 * 64 + lane]);
            float a2 = __half2float(g[(size_t)u2 * 64 + lane]);
            float a3 = __half2float(g[(size_t)u3 * 64 + lane]);
            acc += (a0 + a1) + (a2 + a3);
        }
        for (; e < cn; e++) {
            int u = __builtin_nontemporal_load(&csr[st + e]);
            acc += __half2float(g[(size_t)u * 64 + lane]);
        }
    }
    zs[wv][lane] = acc;   // wave-private: no barrier
    if (node < n) {
        float t = 0.f;
#pragma unroll
        for (int q = 0; q < 16; q++) {
            float4 wv4 = wq[q][lane];                      // per-lane b128
            float4 zq = *(const float4*)&zs[wv][q * 4];    // uniform b128 (broadcast)
            t += zq.x * wv4.x + zq.y * wv4.y + zq.z * wv4.z + zq.w * wv4.w;
        }
        float o = dv * t + bs[lane];
        o = fmaxf(o, 0.f);
        gout[(size_t)node * 64 + lane] = __float2half_rn(dv * o);
    }
}

// ---------------- Layer-4 transform: s4 = g3 @ W4  (dinv cancels exactly) ----------------
__global__ __launch_bounds__(128) void gemm16_kernel(const __half* __restrict__ xin,
                                                     const float* __restrict__ W,
                                                     __half* __restrict__ s, int n) {
    constexpr int DOUT = 16;
    constexpr int ROWS = 128;
    __shared__ float xs[ROWS][65];
    __shared__ float ws[64][DOUT];
    int tid = threadIdx.x;
    int row0 = blockIdx.x * ROWS;
    for (int i = tid; i < 64 * DOUT; i += 128) ws[i / DOUT][i % DOUT] = W[i];
    for (int i = tid; i < ROWS * 16; i += 128) {
        int r = i >> 4, c = (i & 15) * 4;
        float4 v = make_float4(0.f, 0.f, 0.f, 0.f);
        if (row0 + r < n) {
            const __half* hp = xin + (size_t)(row0 + r) * 64 + c;
            float2 f01 = __half22float2(*(const __half2*)hp);
            float2 f23 = __half22float2(*(const __half2*)(hp + 2));
            v = make_float4(f01.x, f01.y, f23.x, f23.y);
        }
        xs[r][c] = v.x; xs[r][c + 1] = v.y; xs[r][c + 2] = v.z; xs[r][c + 3] = v.w;
    }
    __syncthreads();
    int rbase = tid;
    float acc[16];
#pragma unroll
    for (int j = 0; j < 16; j++) acc[j] = 0.f;
    for (int k = 0; k < 64; k++) {
        float xv = xs[rbase][k];
#pragma unroll
        for (int j = 0; j < 4; j++) {
            float4 wv = *(const float4*)&ws[k][j * 4];
            acc[j * 4 + 0] += xv * wv.x;
            acc[j * 4 + 1] += xv * wv.y;
            acc[j * 4 + 2] += xv * wv.z;
            acc[j * 4 + 3] += xv * wv.w;
        }
    }
    int r = row0 + rbase;
    if (r < n) {
        union { ushort u[16]; uint4 q[2]; } pk;
#pragma unroll
        for (int j = 0; j < 16; j++)
            pk.u[j] = __half_as_ushort(__float2half_rn(acc[j]));
        uint4* sp = (uint4*)&s[(size_t)r * DOUT];
        sp[0] = pk.q[0];
        sp[1] = pk.q[1];
    }
}

// ---------------- Layer-4 aggregate: out = dinv*(sum s4) + b4, fp32 ----------------
__global__ __launch_bounds__(256) void agg16_kernel(const __half* __restrict__ s,
                                                    const int* __restrict__ csr,
                                                    const int* __restrict__ start,
                                                    const int* __restrict__ cnt,
                                                    const float* __restrict__ dinv,
                                                    const float* __restrict__ bias,
                                                    float* __restrict__ out, int n) {
    constexpr int D = 16;
    int tid = threadIdx.x;
    int lane = tid & 63;
    int wave = tid >> 6;
    int col = lane % D;
    int grp = lane / D;
    int node = (blockIdx.x * 4 + wave) * 4 + grp;
    if (node >= n) return;
    int st = start[node];
    int cn = cnt[node];
    float acc = __half2float(s[(size_t)node * D + col]);  // self loop
    int e = 0;
    for (; e + 7 < cn; e += 8) {
        int u[8]; float a[8];
#pragma unroll
        for (int j = 0; j < 8; j++) u[j] = __builtin_nontemporal_load(&csr[st + e + j]);
#pragma unroll
        for (int j = 0; j < 8; j++) a[j] = __half2float(s[(size_t)u[j] * D + col]);
        acc += ((a[0] + a[1]) + (a[2] + a[3])) + ((a[4] + a[5]) + (a[6] + a[7]));
    }
    for (; e + 3 < cn; e += 4) {
        int u0 = __builtin_nontemporal_load(&csr[st + e + 0]);
        int u1 = __builtin_nontemporal_load(&csr[st + e + 1]);
        int u2 = __builtin_nontemporal_load(&csr[st + e + 2]);
        int u3 = __builtin_nontemporal_load(&csr[st + e + 3]);
        float a0 = __half2float(s[(size_t)u0 * D + col]);
        float a1 = __half2float(s[(size_t)u1 * D + col]);
        float a2 = __half2float(s[(size_t)u2 * D + col]);
        float a3 = __half2float(s[(size_t)u3 * D + col]);
        acc += (a0 + a1) + (a2 + a3);
    }
    for (; e < cn; e++) {
        int u = __builtin_nontemporal_load(&csr[st + e]);
        acc += __half2float(s[(size_t)u * D + col]);
    }
    float o = dinv[node] * acc + bias[col];
    __builtin_nontemporal_store(o, out + (size_t)node * D + col);
}

// ---------------- launch ----------------

extern "C" void kernel_launch(void* const* d_in, const int* in_sizes, int n_in,
                              void* d_out, int out_size, void* d_ws, size_t ws_size,
                              hipStream_t stream) {
    const float* x  = (const float*)d_in[0];
    const int* ei   = (const int*)d_in[1];
    const float* W1 = (const float*)d_in[2];
    const float* b1 = (const float*)d_in[3];
    const float* W2 = (const float*)d_in[4];
    const float* b2 = (const float*)d_in[5];
    const float* W3 = (const float*)d_in[6];
    const float* b3 = (const float*)d_in[7];
    const float* W4 = (const float*)d_in[8];
    const float* b4 = (const float*)d_in[9];
    const int* src = ei;
    const int* dst = ei + NE;

    char* w = (char*)d_ws;
    float* dinv  = (float*)w;         w += (size_t)NN * 4;
    int* cnt     = (int*)w;           w += (size_t)NN * 4;
    int* start   = (int*)w;           w += (size_t)NN * 4;
    int* bcnt    = (int*)w;           w += (size_t)(NBKT + 4) * 4;
    int* bbase   = (int*)w;           w += (size_t)(NBKT + 4) * 4;
    int* bcur    = (int*)w;           w += (size_t)(NBKT + 4) * 4;
    int* csr     = (int*)w;           w += (size_t)NE * 4;
    __half* gA   = (__half*)w;        w += (size_t)NN * 64 * 2;
    __half* gB   = (__half*)w;        w += (size_t)NN * 64 * 2;
    __half* s4   = (__half*)w;        w += (size_t)NN * 16 * 2;
    int2* bedges = (int2*)w;          w += (size_t)NE * 8;

    zero_small_kernel<<<1, 256, 0, stream>>>(bcnt, NBKT);
    bhist_kernel<<<512, 256, 0, stream>>>(dst, bcnt, NE);
    bscan_kernel<<<1, 256, 0, stream>>>(bcnt, bbase, bcur);
    bscatter_kernel<<<(NE + 2047) / 2048, 256, 0, stream>>>(src, dst, bcur, bedges, NE);
    bfill_kernel<<<NBKT, 512, 0, stream>>>(bedges, bbase, start, cnt, dinv, csr);

    prep_kernel<<<(NN * 16 + 255) / 256, 256, 0, stream>>>(x, dinv, gA);

    const int FB = (NN + 7) / 8;      // 12500 blocks, 1 node/wave
    fused_layer_kernel<<<FB, 512, 0, stream>>>(gA, csr, start, cnt, dinv, W1, b1, gB, NN);
    fused_layer_kernel<<<FB, 512, 0, stream>>>(gB, csr, start, cnt, dinv, W2, b2, gA, NN);
    fused_layer_kernel<<<FB, 512, 0, stream>>>(gA, csr, start, cnt, dinv, W3, b3, gB, NN);

    const int GB = (NN + 127) / 128;
    const int AB16 = (NN + 15) / 16;
    gemm16_kernel<<<GB, 128, 0, stream>>>(gB, W4, s4, NN);
    agg16_kernel<<<AB16, 256, 0, stream>>>(s4, csr, start, cnt, dinv, b4, (float*)d_out, NN);
}

// Round 10
// 359.903 us; speedup vs baseline: 2.6276x; 1.0609x over previous
//
#include <hip/hip_runtime.h>
#include <hip/hip_fp16.h>

#define NN 100000
#define NE 1600000
#define BK 512          // nodes per bucket (CSR build)
#define BKSH 9          // log2(BK)
#define NBKT 196        // ceil(NN/BK)
#define SRCMASK 0x1FFFF // 17 bits (NN < 131072)

typedef _Float16 half2v __attribute__((ext_vector_type(2)));

__device__ inline float dot2acc(unsigned int a, unsigned int b, float c) {
#if __has_builtin(__builtin_amdgcn_fdot2)
    union { unsigned int u; half2v h; } ua, ub;
    ua.u = a; ub.u = b;
    return __builtin_amdgcn_fdot2(ua.h, ub.h, c, false);
#else
    float2 fa = __half22float2(*(const __half2*)&a);
    float2 fb = __half22float2(*(const __half2*)&b);
    return c + fa.x * fb.x + fa.y * fb.y;
#endif
}

__device__ inline int wave_incl_scan(int v, int lane) {
#pragma unroll
    for (int off = 1; off < 64; off <<= 1) {
        int t = __shfl_up(v, off, 64);
        if (lane >= off) v += t;
    }
    return v;
}

// ---------------- Bucketed CSR build ----------------

__global__ __launch_bounds__(256) void zero_small_kernel(int* __restrict__ p, int n) {
    int i = threadIdx.x + blockIdx.x * 256;
    if (i < n) p[i] = 0;
}

__global__ __launch_bounds__(256) void bhist_kernel(const int* __restrict__ dst,
                                                    int* __restrict__ bcnt, int e) {
    __shared__ int h[4 * NBKT];
    int tid = threadIdx.x;
    int wv = tid >> 6;
    for (int i = tid; i < 4 * NBKT; i += 256) h[i] = 0;
    __syncthreads();
    for (int i = blockIdx.x * 256 + tid; i < e; i += gridDim.x * 256)
        atomicAdd(&h[wv * NBKT + (__builtin_nontemporal_load(&dst[i]) >> BKSH)], 1);
    __syncthreads();
    for (int i = tid; i < NBKT; i += 256) {
        int s = h[i] + h[NBKT + i] + h[2 * NBKT + i] + h[3 * NBKT + i];
        if (s) atomicAdd(&bcnt[i], s);
    }
}

__global__ __launch_bounds__(256) void bscan_kernel(const int* __restrict__ bcnt,
                                                    int* __restrict__ bbase,
                                                    int* __restrict__ bcur) {
    __shared__ int sc[256];
    int tid = threadIdx.x;
    int v = (tid < NBKT) ? bcnt[tid] : 0;
    sc[tid] = v;
    __syncthreads();
    for (int off = 1; off < 256; off <<= 1) {
        int t2 = (tid >= off) ? sc[tid - off] : 0;
        __syncthreads();
        sc[tid] += t2;
        __syncthreads();
    }
    if (tid < NBKT) {
        int ex = sc[tid] - v;
        bbase[tid] = ex;
        bcur[tid] = ex;
    }
    if (tid == 255) bbase[NBKT] = sc[255];
}

// Counting-sort edges into dst-bucket order, packed 4B entries, wave scans.
__global__ __launch_bounds__(256) void bscatter_kernel(const int* __restrict__ src,
                                                       const int* __restrict__ dst,
                                                       int* __restrict__ bcur,
                                                       unsigned int* __restrict__ bedges,
                                                       int e) {
    __shared__ int h[256];
    __shared__ int sc[256];
    __shared__ int gb[NBKT];
    __shared__ int wsum[4];
    __shared__ int wexc[4];
    __shared__ int2 stg[2048];   // {packed, bucket}
    int tid = threadIdx.x, lane = tid & 63, wv = tid >> 6;
    int tile = blockIdx.x * 2048;
    int cnt_tile = min(2048, e - tile);
    h[tid] = 0;
    __syncthreads();
    unsigned int pk[8]; int rk[8], bk[8];
#pragma unroll
    for (int j = 0; j < 8; j++) {
        int li = tid + j * 256;
        if (li < cnt_tile) {
            int s = src[tile + li];
            int d = dst[tile + li];
            bk[j] = d >> BKSH;
            pk[j] = ((unsigned)(d & (BK - 1)) << 17) | (unsigned)s;
            rk[j] = atomicAdd(&h[bk[j]], 1);
        } else bk[j] = -1;
    }
    __syncthreads();
    int v = h[tid];
    int incl = wave_incl_scan(v, lane);
    if (lane == 63) wsum[wv] = incl;
    __syncthreads();
    if (tid == 0) {
        int r = 0;
#pragma unroll
        for (int q = 0; q < 4; q++) { wexc[q] = r; r += wsum[q]; }
    }
    __syncthreads();
    int excl = incl - v + wexc[wv];
    sc[tid] = excl;
    if (tid < NBKT && v > 0) gb[tid] = atomicAdd(&bcur[tid], v);
    __syncthreads();
#pragma unroll
    for (int j = 0; j < 8; j++)
        if (bk[j] >= 0) stg[sc[bk[j]] + rk[j]] = make_int2((int)pk[j], bk[j]);
    __syncthreads();
#pragma unroll
    for (int j = 0; j < 8; j++) {
        int li = tid + j * 256;
        if (li < cnt_tile) {
            int2 p2 = stg[li];
            bedges[gb[p2.y] + (li - sc[p2.y])] = (unsigned int)p2.x;
        }
    }
}

// One 512-thread block per bucket: LDS hist + wave scan + cursor scatter.
__global__ __launch_bounds__(512) void bfill_kernel(const unsigned int* __restrict__ bedges,
                                                    const int* __restrict__ bbase,
                                                    int* __restrict__ start,
                                                    int* __restrict__ cnt,
                                                    float* __restrict__ dinv,
                                                    int* __restrict__ csr) {
    __shared__ int lcnt[BK];
    __shared__ int lcur[BK];
    __shared__ int wsum[8];
    __shared__ int wexc[8];
    int q = blockIdx.x, tid = threadIdx.x, lane = tid & 63, wv = tid >> 6;
    int ebase = bbase[q], ec = bbase[q + 1] - ebase;
    int nbase = q * BK;
    lcnt[tid] = 0;
    __syncthreads();
    for (int i = tid; i < ec; i += 512)
        atomicAdd(&lcnt[__builtin_nontemporal_load(&bedges[ebase + i]) >> 17], 1);
    __syncthreads();
    int v = lcnt[tid];
    int incl = wave_incl_scan(v, lane);
    if (lane == 63) wsum[wv] = incl;
    __syncthreads();
    if (tid == 0) {
        int r = 0;
#pragma unroll
        for (int p = 0; p < 8; p++) { wexc[p] = r; r += wsum[p]; }
    }
    __syncthreads();
    int ex = incl - v + wexc[wv];
    lcur[tid] = ex;
    int nd = nbase + tid;
    if (nd < NN) {
        start[nd] = ebase + ex;
        cnt[nd]   = v;
        dinv[nd]  = rsqrtf((float)v + 1.0f);
    }
    __syncthreads();
    for (int i = tid; i < ec; i += 512) {
        unsigned int pk = __builtin_nontemporal_load(&bedges[ebase + i]);
        int r = atomicAdd(&lcur[pk >> 17], 1);
        csr[ebase + r] = (int)(pk & SRCMASK);
    }
}

// ---------------- prep: g0 = fp16(dinv .* x) ----------------
__global__ __launch_bounds__(256) void prep_kernel(const float* __restrict__ x,
                                                   const float* __restrict__ dinv,
                                                   __half* __restrict__ g) {
    size_t i4 = (size_t)blockIdx.x * 256 + threadIdx.x;   // float4 index
    if (i4 >= (size_t)NN * 16) return;
    int row = (int)(i4 >> 4);
    float dv = dinv[row];
    float4 v = *(const float4*)&x[i4 * 4];
    __half2 h01 = __floats2half2_rn(v.x * dv, v.y * dv);
    __half2 h23 = __floats2half2_rn(v.z * dv, v.w * dv);
    __half2* gp = (__half2*)&g[i4 * 4];
    gp[0] = h01;
    gp[1] = h23;
}

// ---------------- Fused layer (1-3): gather + 64x64 transform ----------------
// 1 node/wave (proven 20-VGPR gather), no post-gather barrier. W in LDS as
// packed half2 (uint4 = 8 halves/col-chunk), z written fp16: matvec is
// 8 per-lane b128 + 8 uniform b128 + 32 v_dot2_f32_f16 per node.
__global__ __launch_bounds__(512) void fused_layer_kernel(const __half* __restrict__ g,
                                                          const int* __restrict__ csr,
                                                          const int* __restrict__ start,
                                                          const int* __restrict__ cnt,
                                                          const float* __restrict__ dinv,
                                                          const float* __restrict__ Wg,
                                                          const float* __restrict__ bias,
                                                          __half* __restrict__ gout, int n) {
    __shared__ uint4 wpk[8][64];   // 8KB: wpk[p][c] = half W[8p..8p+7][c]
    __shared__ __half zh[8][64];   // 1KB, one row per wave
    __shared__ float bs[64];
    int tid = threadIdx.x;
    {   // stage W as half2-packed; coalesced per row (c = tid&63 consecutive)
        int p = tid >> 6, c = tid & 63;
        float w[8];
#pragma unroll
        for (int i = 0; i < 8; i++) w[i] = Wg[(8 * p + i) * 64 + c];
        union { __half2 h; unsigned int u; } u0, u1, u2, u3;
        u0.h = __floats2half2_rn(w[0], w[1]);
        u1.h = __floats2half2_rn(w[2], w[3]);
        u2.h = __floats2half2_rn(w[4], w[5]);
        u3.h = __floats2half2_rn(w[6], w[7]);
        wpk[p][c] = make_uint4(u0.u, u1.u, u2.u, u3.u);
    }
    if (tid < 64) bs[tid] = bias[tid];
    __syncthreads();   // only barrier: W/bias staging

    int wv = tid >> 6, lane = tid & 63;
    int node = blockIdx.x * 8 + wv;
    float acc = 0.f;
    float dv = 0.f;
    if (node < n) {
        int st = __builtin_amdgcn_readfirstlane(start[node]);
        int cn = __builtin_amdgcn_readfirstlane(cnt[node]);
        dv = dinv[node];
        acc = __half2float(g[(size_t)node * 64 + lane]);  // self loop
        int e = 0;
        for (; e + 7 < cn; e += 8) {
            int u[8]; float a[8];
#pragma unroll
            for (int j = 0; j < 8; j++) u[j] = __builtin_nontemporal_load(&csr[st + e + j]);
#pragma unroll
            for (int j = 0; j < 8; j++) a[j] = __half2float(g[(size_t)u[j] * 64 + lane]);
            acc += ((a[0] + a[1]) + (a[2] + a[3])) + ((a[4] + a[5]) + (a[6] + a[7]));
        }
        for (; e + 3 < cn; e += 4) {
            int u0 = __builtin_nontemporal_load(&csr[st + e + 0]);
            int u1 = __builtin_nontemporal_load(&csr[st + e + 1]);
            int u2 = __builtin_nontemporal_load(&csr[st + e + 2]);
            int u3 = __builtin_nontemporal_load(&csr[st + e + 3]);
            float a0 = __half2float(g[(size_t)u0 * 64 + lane]);
            float a1 = __half2float(g[(size_t)u1 * 64 + lane]);
            float a2 = __half2float(g[(size_t)u2 * 64 + lane]);
            float a3 = __half2float(g[(size_t)u3 * 64 + lane]);
            acc += (a0 + a1) + (a2 + a3);
        }
        for (; e < cn; e++) {
            int u = __builtin_nontemporal_load(&csr[st + e]);
            acc += __half2float(g[(size_t)u * 64 + lane]);
        }
    }
    zh[wv][lane] = __float2half_rn(acc);   // wave-private: no barrier
    if (node < n) {
        float t = 0.f;
#pragma unroll
        for (int p = 0; p < 8; p++) {
            uint4 wq = wpk[p][lane];                        // per-lane b128
            uint4 zq = *(const uint4*)&zh[wv][p * 8];       // uniform b128
            t = dot2acc(zq.x, wq.x, t);
            t = dot2acc(zq.y, wq.y, t);
            t = dot2acc(zq.z, wq.z, t);
            t = dot2acc(zq.w, wq.w, t);
        }
        float o = dv * t + bs[lane];
        o = fmaxf(o, 0.f);
        gout[(size_t)node * 64 + lane] = __float2half_rn(dv * o);
    }
}

// ---------------- Layer-4 transform: s4 = g3 @ W4  (dinv cancels exactly) ----------------
__global__ __launch_bounds__(128) void gemm16_kernel(const __half* __restrict__ xin,
                                                     const float* __restrict__ W,
                                                     __half* __restrict__ s, int n) {
    constexpr int DOUT = 16;
    constexpr int ROWS = 128;
    __shared__ float xs[ROWS][65];
    __shared__ float ws[64][DOUT];
    int tid = threadIdx.x;
    int row0 = blockIdx.x * ROWS;
    for (int i = tid; i < 64 * DOUT; i += 128) ws[i / DOUT][i % DOUT] = W[i];
    for (int i = tid; i < ROWS * 16; i += 128) {
        int r = i >> 4, c = (i & 15) * 4;
        float4 v = make_float4(0.f, 0.f, 0.f, 0.f);
        if (row0 + r < n) {
            const __half* hp = xin + (size_t)(row0 + r) * 64 + c;
            float2 f01 = __half22float2(*(const __half2*)hp);
            float2 f23 = __half22float2(*(const __half2*)(hp + 2));
            v = make_float4(f01.x, f01.y, f23.x, f23.y);
        }
        xs[r][c] = v.x; xs[r][c + 1] = v.y; xs[r][c + 2] = v.z; xs[r][c + 3] = v.w;
    }
    __syncthreads();
    int rbase = tid;
    float acc[16];
#pragma unroll
    for (int j = 0; j < 16; j++) acc[j] = 0.f;
    for (int k = 0; k < 64; k++) {
        float xv = xs[rbase][k];
#pragma unroll
        for (int j = 0; j < 4; j++) {
            float4 wv = *(const float4*)&ws[k][j * 4];
            acc[j * 4 + 0] += xv * wv.x;
            acc[j * 4 + 1] += xv * wv.y;
            acc[j * 4 + 2] += xv * wv.z;
            acc[j * 4 + 3] += xv * wv.w;
        }
    }
    int r = row0 + rbase;
    if (r < n) {
        union { ushort u[16]; uint4 q[2]; } pk;
#pragma unroll
        for (int j = 0; j < 16; j++)
            pk.u[j] = __half_as_ushort(__float2half_rn(acc[j]));
        uint4* sp = (uint4*)&s[(size_t)r * DOUT];
        sp[0] = pk.q[0];
        sp[1] = pk.q[1];
    }
}

// ---------------- Layer-4 aggregate: out = dinv*(sum s4) + b4, fp32 ----------------
__global__ __launch_bounds__(256) void agg16_kernel(const __half* __restrict__ s,
                                                    const int* __restrict__ csr,
                                                    const int* __restrict__ start,
                                                    const int* __restrict__ cnt,
                                                    const float* __restrict__ dinv,
                                                    const float* __restrict__ bias,
                                                    float* __restrict__ out, int n) {
    constexpr int D = 16;
    int tid = threadIdx.x;
    int lane = tid & 63;
    int wave = tid >> 6;
    int col = lane % D;
    int grp = lane / D;
    int node = (blockIdx.x * 4 + wave) * 4 + grp;
    if (node >= n) return;
    int st = start[node];
    int cn = cnt[node];
    float acc = __half2float(s[(size_t)node * D + col]);  // self loop
    int e = 0;
    for (; e + 7 < cn; e += 8) {
        int u[8]; float a[8];
#pragma unroll
        for (int j = 0; j < 8; j++) u[j] = __builtin_nontemporal_load(&csr[st + e + j]);
#pragma unroll
        for (int j = 0; j < 8; j++) a[j] = __half2float(s[(size_t)u[j] * D + col]);
        acc += ((a[0] + a[1]) + (a[2] + a[3])) + ((a[4] + a[5]) + (a[6] + a[7]));
    }
    for (; e + 3 < cn; e += 4) {
        int u0 = __builtin_nontemporal_load(&csr[st + e + 0]);
        int u1 = __builtin_nontemporal_load(&csr[st + e + 1]);
        int u2 = __builtin_nontemporal_load(&csr[st + e + 2]);
        int u3 = __builtin_nontemporal_load(&csr[st + e + 3]);
        float a0 = __half2float(s[(size_t)u0 * D + col]);
        float a1 = __half2float(s[(size_t)u1 * D + col]);
        float a2 = __half2float(s[(size_t)u2 * D + col]);
        float a3 = __half2float(s[(size_t)u3 * D + col]);
        acc += (a0 + a1) + (a2 + a3);
    }
    for (; e < cn; e++) {
        int u = __builtin_nontemporal_load(&csr[st + e]);
        acc += __half2float(s[(size_t)u * D + col]);
    }
    float o = dinv[node] * acc + bias[col];
    __builtin_nontemporal_store(o, out + (size_t)node * D + col);
}

// ---------------- launch ----------------

extern "C" void kernel_launch(void* const* d_in, const int* in_sizes, int n_in,
                              void* d_out, int out_size, void* d_ws, size_t ws_size,
                              hipStream_t stream) {
    const float* x  = (const float*)d_in[0];
    const int* ei   = (const int*)d_in[1];
    const float* W1 = (const float*)d_in[2];
    const float* b1 = (const float*)d_in[3];
    const float* W2 = (const float*)d_in[4];
    const float* b2 = (const float*)d_in[5];
    const float* W3 = (const float*)d_in[6];
    const float* b3 = (const float*)d_in[7];
    const float* W4 = (const float*)d_in[8];
    const float* b4 = (const float*)d_in[9];
    const int* src = ei;
    const int* dst = ei + NE;

    char* w = (char*)d_ws;
    float* dinv  = (float*)w;          w += (size_t)NN * 4;
    int* cnt     = (int*)w;            w += (size_t)NN * 4;
    int* start   = (int*)w;            w += (size_t)NN * 4;
    int* bcnt    = (int*)w;            w += (size_t)(NBKT + 4) * 4;
    int* bbase   = (int*)w;            w += (size_t)(NBKT + 4) * 4;
    int* bcur    = (int*)w;            w += (size_t)(NBKT + 4) * 4;
    int* csr     = (int*)w;            w += (size_t)NE * 4;
    __half* gA   = (__half*)w;         w += (size_t)NN * 64 * 2;
    __half* gB   = (__half*)w;         w += (size_t)NN * 64 * 2;
    __half* s4   = (__half*)w;         w += (size_t)NN * 16 * 2;
    unsigned int* bedges = (unsigned int*)w;  w += (size_t)NE * 4;

    zero_small_kernel<<<1, 256, 0, stream>>>(bcnt, NBKT);
    bhist_kernel<<<512, 256, 0, stream>>>(dst, bcnt, NE);
    bscan_kernel<<<1, 256, 0, stream>>>(bcnt, bbase, bcur);
    bscatter_kernel<<<(NE + 2047) / 2048, 256, 0, stream>>>(src, dst, bcur, bedges, NE);
    bfill_kernel<<<NBKT, 512, 0, stream>>>(bedges, bbase, start, cnt, dinv, csr);

    prep_kernel<<<(NN * 16 + 255) / 256, 256, 0, stream>>>(x, dinv, gA);

    const int FB = (NN + 7) / 8;      // 12500 blocks, 1 node/wave
    fused_layer_kernel<<<FB, 512, 0, stream>>>(gA, csr, start, cnt, dinv, W1, b1, gB, NN);
    fused_layer_kernel<<<FB, 512, 0, stream>>>(gB, csr, start, cnt, dinv, W2, b2, gA, NN);
    fused_layer_kernel<<<FB, 512, 0, stream>>>(gA, csr, start, cnt, dinv, W3, b3, gB, NN);

    const int GB = (NN + 127) / 128;
    const int AB16 = (NN + 15) / 16;
    gemm16_kernel<<<GB, 128, 0, stream>>>(gB, W4, s4, NN);
    agg16_kernel<<<AB16, 256, 0, stream>>>(s4, csr, start, cnt, dinv, b4, (float*)d_out, NN);
}

// Round 11
// 338.764 us; speedup vs baseline: 2.7916x; 1.0624x over previous
//
#include <hip/hip_runtime.h>
#include <hip/hip_fp16.h>

#define NN 100000
#define NE 1600000
#define BK 512           // nodes per bucket
#define BKSH 9           // log2(BK)
#define NBKT 196         // ceil(NN/BK)
#define SLOT 9216        // fixed edge capacity per bucket (mean 8192, sigma~90)
#define SRCMASK 0x1FFFF  // 17 bits (NN < 131072)

typedef _Float16 half2v __attribute__((ext_vector_type(2)));

__device__ inline float dot2acc(unsigned int a, unsigned int b, float c) {
#if __has_builtin(__builtin_amdgcn_fdot2)
    union { unsigned int u; half2v h; } ua, ub;
    ua.u = a; ub.u = b;
    return __builtin_amdgcn_fdot2(ua.h, ub.h, c, false);
#else
    float2 fa = __half22float2(*(const __half2*)&a);
    float2 fb = __half22float2(*(const __half2*)&b);
    return c + fa.x * fb.x + fa.y * fb.y;
#endif
}

__device__ inline int wave_incl_scan(int v, int lane) {
#pragma unroll
    for (int off = 1; off < 64; off <<= 1) {
        int t = __shfl_up(v, off, 64);
        if (lane >= off) v += t;
    }
    return v;
}

// ---------------- CSR build: fixed-slot buckets (no global hist/scan) ----------------

__global__ __launch_bounds__(256) void zero_small_kernel(int* __restrict__ p, int n) {
    int i = threadIdx.x + blockIdx.x * 256;
    if (i < n) p[i] = 0;
}

// 4096-edge tiles, 512 threads. Per-tile LDS hist + single-wave scan over the
// 196 buckets, LDS reorder, near-coalesced copy-out into fixed bucket slots.
__global__ __launch_bounds__(512) void bscatter_kernel(const int* __restrict__ src,
                                                       const int* __restrict__ dst,
                                                       int* __restrict__ bcur,
                                                       unsigned int* __restrict__ bedges,
                                                       int e) {
    __shared__ int h[256];
    __shared__ int sc[256];
    __shared__ int gb[256];
    __shared__ int2 stg[4096];   // {packed, bucket}
    int tid = threadIdx.x;
    int tile = blockIdx.x * 4096;
    int cnt_tile = min(4096, e - tile);
    if (tid < 256) h[tid] = 0;
    __syncthreads();
    unsigned int pk[8]; int rk[8], bk[8];
#pragma unroll
    for (int j = 0; j < 8; j++) {
        int li = tid + j * 512;
        if (li < cnt_tile) {
            int s = src[tile + li];
            int d = dst[tile + li];
            bk[j] = d >> BKSH;
            pk[j] = ((unsigned)(d & (BK - 1)) << 17) | (unsigned)s;
            rk[j] = atomicAdd(&h[bk[j]], 1);
        } else bk[j] = -1;
    }
    __syncthreads();
    if (tid < 64) {   // single-wave scan: 4 buckets/lane
        int b0 = tid * 4;
        int c0 = h[b0], c1 = h[b0 + 1], c2 = h[b0 + 2], c3 = h[b0 + 3];
        int s4 = c0 + c1 + c2 + c3;
        int incl = wave_incl_scan(s4, tid);
        int base = incl - s4;
        sc[b0] = base; sc[b0 + 1] = base + c0;
        sc[b0 + 2] = base + c0 + c1; sc[b0 + 3] = base + c0 + c1 + c2;
        if (c0) gb[b0] = atomicAdd(&bcur[b0], c0);
        if (c1) gb[b0 + 1] = atomicAdd(&bcur[b0 + 1], c1);
        if (c2) gb[b0 + 2] = atomicAdd(&bcur[b0 + 2], c2);
        if (c3) gb[b0 + 3] = atomicAdd(&bcur[b0 + 3], c3);
    }
    __syncthreads();
#pragma unroll
    for (int j = 0; j < 8; j++)
        if (bk[j] >= 0) stg[sc[bk[j]] + rk[j]] = make_int2((int)pk[j], bk[j]);
    __syncthreads();
#pragma unroll
    for (int j = 0; j < 8; j++) {
        int li = tid + j * 512;
        if (li < cnt_tile) {
            int2 p2 = stg[li];
            int b = p2.y;
            bedges[(size_t)b * SLOT + gb[b] + (li - sc[b])] = (unsigned int)p2.x;
        }
    }
}

// One 1024-thread block per bucket: LDS hist + single-wave scan + cursor scatter.
__global__ __launch_bounds__(1024) void bfill_kernel(const unsigned int* __restrict__ bedges,
                                                     const int* __restrict__ bcur,
                                                     int* __restrict__ start,
                                                     int* __restrict__ cnt,
                                                     float* __restrict__ dinv,
                                                     int* __restrict__ csr) {
    __shared__ int lcnt[BK];
    __shared__ int lstart[BK];
    __shared__ int lcur[BK];
    int q = blockIdx.x, tid = threadIdx.x;
    size_t ebase = (size_t)q * SLOT;
    int ec = bcur[q];
    int nbase = q * BK;
    if (tid < BK) lcnt[tid] = 0;
    __syncthreads();
    for (int i = tid; i < ec; i += 1024)
        atomicAdd(&lcnt[__builtin_nontemporal_load(&bedges[ebase + i]) >> 17], 1);
    __syncthreads();
    if (tid < 64) {   // single-wave scan: 8 buckets/lane
        int b0 = tid * 8;
        int c[8]; int s = 0;
#pragma unroll
        for (int k = 0; k < 8; k++) { c[k] = lcnt[b0 + k]; s += c[k]; }
        int incl = wave_incl_scan(s, tid);
        int run = incl - s;
#pragma unroll
        for (int k = 0; k < 8; k++) { lstart[b0 + k] = run; lcur[b0 + k] = run; run += c[k]; }
    }
    __syncthreads();
    if (tid < BK) {
        int nd = nbase + tid;
        if (nd < NN) {
            start[nd] = (int)ebase + lstart[tid];
            cnt[nd]   = lcnt[tid];
            dinv[nd]  = rsqrtf((float)lcnt[tid] + 1.0f);
        }
    }
    for (int i = tid; i < ec; i += 1024) {
        unsigned int pk = __builtin_nontemporal_load(&bedges[ebase + i]);
        int r = atomicAdd(&lcur[pk >> 17], 1);
        csr[ebase + r] = (int)(pk & SRCMASK);
    }
}

// ---------------- prep: g0 = fp16(dinv .* x) ----------------
__global__ __launch_bounds__(256) void prep_kernel(const float* __restrict__ x,
                                                   const float* __restrict__ dinv,
                                                   __half* __restrict__ g) {
    size_t i4 = (size_t)blockIdx.x * 256 + threadIdx.x;   // float4 index
    if (i4 >= (size_t)NN * 16) return;
    int row = (int)(i4 >> 4);
    float dv = dinv[row];
    float4 v = *(const float4*)&x[i4 * 4];
    __half2 h01 = __floats2half2_rn(v.x * dv, v.y * dv);
    __half2 h23 = __floats2half2_rn(v.z * dv, v.w * dv);
    __half2* gp = (__half2*)&g[i4 * 4];
    gp[0] = h01;
    gp[1] = h23;
}

// ---------------- Fused layer (1-3): gather + 64x64 transform (R10, unchanged) ----------------
__global__ __launch_bounds__(512) void fused_layer_kernel(const __half* __restrict__ g,
                                                          const int* __restrict__ csr,
                                                          const int* __restrict__ start,
                                                          const int* __restrict__ cnt,
                                                          const float* __restrict__ dinv,
                                                          const float* __restrict__ Wg,
                                                          const float* __restrict__ bias,
                                                          __half* __restrict__ gout, int n) {
    __shared__ uint4 wpk[8][64];   // 8KB: wpk[p][c] = half W[8p..8p+7][c]
    __shared__ __half zh[8][64];   // 1KB, one row per wave
    __shared__ float bs[64];
    int tid = threadIdx.x;
    {
        int p = tid >> 6, c = tid & 63;
        float w[8];
#pragma unroll
        for (int i = 0; i < 8; i++) w[i] = Wg[(8 * p + i) * 64 + c];
        union { __half2 h; unsigned int u; } u0, u1, u2, u3;
        u0.h = __floats2half2_rn(w[0], w[1]);
        u1.h = __floats2half2_rn(w[2], w[3]);
        u2.h = __floats2half2_rn(w[4], w[5]);
        u3.h = __floats2half2_rn(w[6], w[7]);
        wpk[p][c] = make_uint4(u0.u, u1.u, u2.u, u3.u);
    }
    if (tid < 64) bs[tid] = bias[tid];
    __syncthreads();   // only barrier: W/bias staging

    int wv = tid >> 6, lane = tid & 63;
    int node = blockIdx.x * 8 + wv;
    float acc = 0.f;
    float dv = 0.f;
    if (node < n) {
        int st = __builtin_amdgcn_readfirstlane(start[node]);
        int cn = __builtin_amdgcn_readfirstlane(cnt[node]);
        dv = dinv[node];
        acc = __half2float(g[(size_t)node * 64 + lane]);  // self loop
        int e = 0;
        for (; e + 7 < cn; e += 8) {
            int u[8]; float a[8];
#pragma unroll
            for (int j = 0; j < 8; j++) u[j] = __builtin_nontemporal_load(&csr[st + e + j]);
#pragma unroll
            for (int j = 0; j < 8; j++) a[j] = __half2float(g[(size_t)u[j] * 64 + lane]);
            acc += ((a[0] + a[1]) + (a[2] + a[3])) + ((a[4] + a[5]) + (a[6] + a[7]));
        }
        for (; e + 3 < cn; e += 4) {
            int u0 = __builtin_nontemporal_load(&csr[st + e + 0]);
            int u1 = __builtin_nontemporal_load(&csr[st + e + 1]);
            int u2 = __builtin_nontemporal_load(&csr[st + e + 2]);
            int u3 = __builtin_nontemporal_load(&csr[st + e + 3]);
            float a0 = __half2float(g[(size_t)u0 * 64 + lane]);
            float a1 = __half2float(g[(size_t)u1 * 64 + lane]);
            float a2 = __half2float(g[(size_t)u2 * 64 + lane]);
            float a3 = __half2float(g[(size_t)u3 * 64 + lane]);
            acc += (a0 + a1) + (a2 + a3);
        }
        for (; e < cn; e++) {
            int u = __builtin_nontemporal_load(&csr[st + e]);
            acc += __half2float(g[(size_t)u * 64 + lane]);
        }
    }
    zh[wv][lane] = __float2half_rn(acc);   // wave-private: no barrier
    if (node < n) {
        float t = 0.f;
#pragma unroll
        for (int p = 0; p < 8; p++) {
            uint4 wq = wpk[p][lane];                        // per-lane b128
            uint4 zq = *(const uint4*)&zh[wv][p * 8];       // uniform b128
            t = dot2acc(zq.x, wq.x, t);
            t = dot2acc(zq.y, wq.y, t);
            t = dot2acc(zq.z, wq.z, t);
            t = dot2acc(zq.w, wq.w, t);
        }
        float o = dv * t + bs[lane];
        o = fmaxf(o, 0.f);
        gout[(size_t)node * 64 + lane] = __float2half_rn(dv * o);
    }
}

// ---------------- Layer-4 transform: s4 = g3 @ W4  (dinv cancels exactly) ----------------
__global__ __launch_bounds__(128) void gemm16_kernel(const __half* __restrict__ xin,
                                                     const float* __restrict__ W,
                                                     __half* __restrict__ s, int n) {
    constexpr int DOUT = 16;
    constexpr int ROWS = 128;
    __shared__ float xs[ROWS][65];
    __shared__ float ws[64][DOUT];
    int tid = threadIdx.x;
    int row0 = blockIdx.x * ROWS;
    for (int i = tid; i < 64 * DOUT; i += 128) ws[i / DOUT][i % DOUT] = W[i];
    for (int i = tid; i < ROWS * 16; i += 128) {
        int r = i >> 4, c = (i & 15) * 4;
        float4 v = make_float4(0.f, 0.f, 0.f, 0.f);
        if (row0 + r < n) {
            const __half* hp = xin + (size_t)(row0 + r) * 64 + c;
            float2 f01 = __half22float2(*(const __half2*)hp);
            float2 f23 = __half22float2(*(const __half2*)(hp + 2));
            v = make_float4(f01.x, f01.y, f23.x, f23.y);
        }
        xs[r][c] = v.x; xs[r][c + 1] = v.y; xs[r][c + 2] = v.z; xs[r][c + 3] = v.w;
    }
    __syncthreads();
    int rbase = tid;
    float acc[16];
#pragma unroll
    for (int j = 0; j < 16; j++) acc[j] = 0.f;
    for (int k = 0; k < 64; k++) {
        float xv = xs[rbase][k];
#pragma unroll
        for (int j = 0; j < 4; j++) {
            float4 wv = *(const float4*)&ws[k][j * 4];
            acc[j * 4 + 0] += xv * wv.x;
            acc[j * 4 + 1] += xv * wv.y;
            acc[j * 4 + 2] += xv * wv.z;
            acc[j * 4 + 3] += xv * wv.w;
        }
    }
    int r = row0 + rbase;
    if (r < n) {
        union { ushort u[16]; uint4 q[2]; } pk;
#pragma unroll
        for (int j = 0; j < 16; j++)
            pk.u[j] = __half_as_ushort(__float2half_rn(acc[j]));
        uint4* sp = (uint4*)&s[(size_t)r * DOUT];
        sp[0] = pk.q[0];
        sp[1] = pk.q[1];
    }
}

// ---------------- Layer-4 aggregate: out = dinv*(sum s4) + b4, fp32 ----------------
__global__ __launch_bounds__(256) void agg16_kernel(const __half* __restrict__ s,
                                                    const int* __restrict__ csr,
                                                    const int* __restrict__ start,
                                                    const int* __restrict__ cnt,
                                                    const float* __restrict__ dinv,
                                                    const float* __restrict__ bias,
                                                    float* __restrict__ out, int n) {
    constexpr int D = 16;
    int tid = threadIdx.x;
    int lane = tid & 63;
    int wave = tid >> 6;
    int col = lane % D;
    int grp = lane / D;
    int node = (blockIdx.x * 4 + wave) * 4 + grp;
    if (node >= n) return;
    int st = start[node];
    int cn = cnt[node];
    float acc = __half2float(s[(size_t)node * D + col]);  // self loop
    int e = 0;
    for (; e + 7 < cn; e += 8) {
        int u[8]; float a[8];
#pragma unroll
        for (int j = 0; j < 8; j++) u[j] = __builtin_nontemporal_load(&csr[st + e + j]);
#pragma unroll
        for (int j = 0; j < 8; j++) a[j] = __half2float(s[(size_t)u[j] * D + col]);
        acc += ((a[0] + a[1]) + (a[2] + a[3])) + ((a[4] + a[5]) + (a[6] + a[7]));
    }
    for (; e + 3 < cn; e += 4) {
        int u0 = __builtin_nontemporal_load(&csr[st + e + 0]);
        int u1 = __builtin_nontemporal_load(&csr[st + e + 1]);
        int u2 = __builtin_nontemporal_load(&csr[st + e + 2]);
        int u3 = __builtin_nontemporal_load(&csr[st + e + 3]);
        float a0 = __half2float(s[(size_t)u0 * D + col]);
        float a1 = __half2float(s[(size_t)u1 * D + col]);
        float a2 = __half2float(s[(size_t)u2 * D + col]);
        float a3 = __half2float(s[(size_t)u3 * D + col]);
        acc += (a0 + a1) + (a2 + a3);
    }
    for (; e < cn; e++) {
        int u = __builtin_nontemporal_load(&csr[st + e]);
        acc += __half2float(s[(size_t)u * D + col]);
    }
    float o = dinv[node] * acc + bias[col];
    __builtin_nontemporal_store(o, out + (size_t)node * D + col);
}

// ---------------- launch ----------------

extern "C" void kernel_launch(void* const* d_in, const int* in_sizes, int n_in,
                              void* d_out, int out_size, void* d_ws, size_t ws_size,
                              hipStream_t stream) {
    const float* x  = (const float*)d_in[0];
    const int* ei   = (const int*)d_in[1];
    const float* W1 = (const float*)d_in[2];
    const float* b1 = (const float*)d_in[3];
    const float* W2 = (const float*)d_in[4];
    const float* b2 = (const float*)d_in[5];
    const float* W3 = (const float*)d_in[6];
    const float* b3 = (const float*)d_in[7];
    const float* W4 = (const float*)d_in[8];
    const float* b4 = (const float*)d_in[9];
    const int* src = ei;
    const int* dst = ei + NE;

    char* w = (char*)d_ws;
    float* dinv  = (float*)w;          w += (size_t)NN * 4;
    int* cnt     = (int*)w;            w += (size_t)NN * 4;
    int* start   = (int*)w;            w += (size_t)NN * 4;
    int* bcur    = (int*)w;            w += (size_t)256 * 4;
    int* csr     = (int*)w;            w += (size_t)NBKT * SLOT * 4;   // slotted, gaps ok
    __half* gA   = (__half*)w;         w += (size_t)NN * 64 * 2;
    __half* gB   = (__half*)w;         w += (size_t)NN * 64 * 2;
    __half* s4   = (__half*)w;         w += (size_t)NN * 16 * 2;
    unsigned int* bedges = (unsigned int*)w;  w += (size_t)NBKT * SLOT * 4;

    zero_small_kernel<<<1, 256, 0, stream>>>(bcur, 256);
    bscatter_kernel<<<(NE + 4095) / 4096, 512, 0, stream>>>(src, dst, bcur, bedges, NE);
    bfill_kernel<<<NBKT, 1024, 0, stream>>>(bedges, bcur, start, cnt, dinv, csr);

    prep_kernel<<<(NN * 16 + 255) / 256, 256, 0, stream>>>(x, dinv, gA);

    const int FB = (NN + 7) / 8;      // 12500 blocks, 1 node/wave
    fused_layer_kernel<<<FB, 512, 0, stream>>>(gA, csr, start, cnt, dinv, W1, b1, gB, NN);
    fused_layer_kernel<<<FB, 512, 0, stream>>>(gB, csr, start, cnt, dinv, W2, b2, gA, NN);
    fused_layer_kernel<<<FB, 512, 0, stream>>>(gA, csr, start, cnt, dinv, W3, b3, gB, NN);

    const int GB = (NN + 127) / 128;
    const int AB16 = (NN + 15) / 16;
    gemm16_kernel<<<GB, 128, 0, stream>>>(gB, W4, s4, NN);
    agg16_kernel<<<AB16, 256, 0, stream>>>(s4, csr, start, cnt, dinv, b4, (float*)d_out, NN);
}